// Round 3
// baseline (567.404 us; speedup 1.0000x reference)
//
#include <hip/hip_runtime.h>
#include <hip/hip_bf16.h>

namespace {
constexpr int NPTS  = 65536;   // points per batch
constexpr int KNB   = 16;      // neighbors
constexpr int CMID  = 16;
constexpr int CIN   = 64;
constexpr int CADD  = 3;
constexpr int COUT  = 128;
constexpr int KREAL = 1072;    // 67*16
constexpr int KPAD  = 1088;    // 68*16 (c padded to 68)
constexpr int MT    = 16;      // points per block (16 -> s_p 35 KB -> 4 blocks/CU)
constexpr int PSTR  = 1096;    // LDS row stride, shorts (2192 B: 16-B aligned rows, known-good)
constexpr int NKT   = KPAD / 32;  // 34 K-chunks in stage 2
}

typedef __attribute__((ext_vector_type(8))) __bf16 bf16x8;
typedef __attribute__((ext_vector_type(4))) float f32x4;

union ABFrag { bf16x8 v; uint4 u; };

__device__ __forceinline__ unsigned int pack_bf2(float a, float b) {
  __hip_bfloat162 h = __float22bfloat162_rn(make_float2(a, b));
  return *reinterpret_cast<unsigned int*>(&h);
}

// One-time per launch: W [128][1072] f32 -> bf16 zero-padded [128][1088] in workspace.
__global__ void convert_w(const float* __restrict__ W, unsigned short* __restrict__ Wb) {
  const int o = blockIdx.x;
  for (int k = threadIdx.x; k < KPAD; k += blockDim.x) {
    float v = (k < KREAL) ? W[o * KREAL + k] : 0.0f;
    __hip_bfloat16 h = __float2bfloat16(v);
    Wb[o * KPAD + k] = *reinterpret_cast<unsigned short*>(&h);
  }
}

__global__ __launch_bounds__(256, 4) void pconv_fused(
    const float* __restrict__ feat,        // [2][65536][64]
    const int* __restrict__ nidx,          // [2][65536][16]
    const float* __restrict__ wn,          // [2][65536][16][16]
    const float* __restrict__ addf,        // [2][65536][16][3]
    const float* __restrict__ W,           // [128][1072] f32 (fallback)
    const float* __restrict__ bias,        // [128]
    const unsigned short* __restrict__ Wb, // [128][1088] bf16
    int useWb,
    float* __restrict__ out)               // [2][65536][128]
{
  // Only LDS: the pconv tile. 16 x 1096 shorts = 35072 B -> 4 blocks/CU.
  __shared__ __align__(16) unsigned short s_p[MT * PSTR];

  const int tid  = threadIdx.x;
  const int wid  = tid >> 6;
  const int lane = tid & 63;
  const int q    = lane >> 4;   // quad
  const int l    = lane & 15;

  // ---------------- stage 1: per-point MFMA pconv^T -> LDS ----------------
  // One wave per point (4 points per wave); 16x16x32 MFMA, k zero-padded 16->32.
  // A = wn^T: A[m=j][k=nb]; B = gathered feat: B[k=nb][n=c]; D[m=j][n=c].
  {
    const int actk = (q < 2);   // quads 0,1 supply k=0..15; quads 2,3 zeros
    const f32x4 zacc = {0.f, 0.f, 0.f, 0.f};

#pragma unroll 2
    for (int pl = 0; pl < 4; ++pl) {
      const int p  = wid * 4 + pl;
      const int mg = blockIdx.x * MT + p;
      const int b  = mg >> 16;
      const float* fb = feat + (size_t)b * (NPTS * CIN);

      int nb[8] = {0, 0, 0, 0, 0, 0, 0, 0};
      if (actk) {
        const int4* ip = reinterpret_cast<const int4*>(nidx + (size_t)mg * KNB + q * 8);
        const int4 i0 = ip[0], i1 = ip[1];
        nb[0] = i0.x; nb[1] = i0.y; nb[2] = i0.z; nb[3] = i0.w;
        nb[4] = i1.x; nb[5] = i1.y; nb[6] = i1.z; nb[7] = i1.w;
      }

      // A-frag: element i <-> k=q*8+i; value wn[mg][k][j=l]
      ABFrag afr; afr.u = make_uint4(0, 0, 0, 0);
      if (actk) {
        const float* wp = wn + (size_t)mg * (KNB * CMID) + (q * 8) * CMID + l;
        float w0 = wp[0],        w1 = wp[CMID],     w2 = wp[2 * CMID], w3 = wp[3 * CMID];
        float w4 = wp[4 * CMID], w5 = wp[5 * CMID], w6 = wp[6 * CMID], w7 = wp[7 * CMID];
        afr.u = make_uint4(pack_bf2(w0, w1), pack_bf2(w2, w3),
                           pack_bf2(w4, w5), pack_bf2(w6, w7));
      }

      unsigned short* prow = s_p + p * PSTR;

#pragma unroll
      for (int ct = 0; ct < 4; ++ct) {
        ABFrag bfr; bfr.u = make_uint4(0, 0, 0, 0);
        if (actk) {
          float f0 = fb[(size_t)nb[0] * CIN + ct * 16 + l];
          float f1 = fb[(size_t)nb[1] * CIN + ct * 16 + l];
          float f2 = fb[(size_t)nb[2] * CIN + ct * 16 + l];
          float f3 = fb[(size_t)nb[3] * CIN + ct * 16 + l];
          float f4 = fb[(size_t)nb[4] * CIN + ct * 16 + l];
          float f5 = fb[(size_t)nb[5] * CIN + ct * 16 + l];
          float f6 = fb[(size_t)nb[6] * CIN + ct * 16 + l];
          float f7 = fb[(size_t)nb[7] * CIN + ct * 16 + l];
          bfr.u = make_uint4(pack_bf2(f0, f1), pack_bf2(f2, f3),
                             pack_bf2(f4, f5), pack_bf2(f6, f7));
        }
        const f32x4 d = __builtin_amdgcn_mfma_f32_16x16x32_bf16(afr.v, bfr.v, zacc, 0, 0, 0);
        // D[row=j=q*4+r][col=c=ct*16+l] -> s_p[p][c*16+j], contiguous in r.
        uint2 w2;
        w2.x = pack_bf2(d[0], d[1]);
        w2.y = pack_bf2(d[2], d[3]);
        *reinterpret_cast<uint2*>(prow + (ct * 16 + l) * 16 + q * 4) = w2;
      }

      // additional-features c-tile (c=64..66; col 67 = zero pad)
      {
        ABFrag bfa; bfa.u = make_uint4(0, 0, 0, 0);
        if (actk && l < CADD) {
          const float* ap = addf + (size_t)mg * (KNB * CADD) + (q * 8) * CADD + l;
          float a0 = ap[0],        a1 = ap[CADD],     a2 = ap[2 * CADD], a3 = ap[3 * CADD];
          float a4 = ap[4 * CADD], a5 = ap[5 * CADD], a6 = ap[6 * CADD], a7 = ap[7 * CADD];
          bfa.u = make_uint4(pack_bf2(a0, a1), pack_bf2(a2, a3),
                             pack_bf2(a4, a5), pack_bf2(a6, a7));
        }
        const f32x4 d = __builtin_amdgcn_mfma_f32_16x16x32_bf16(afr.v, bfa.v, zacc, 0, 0, 0);
        if (l < 4) {
          uint2 w2;
          w2.x = pack_bf2(d[0], d[1]);
          w2.y = pack_bf2(d[2], d[3]);
          *reinterpret_cast<uint2*>(prow + (64 + l) * 16 + q * 4) = w2;
        }
      }
    }
  }

  __syncthreads();  // the ONLY barrier: s_p complete, begin GEMM

  // ---------------- stage 2: out[16][128] = pconv[16][1088] @ Wb^T ----------------
  // Barrier-free K-loop: A from LDS, B directly from global (L1/L2-resident W).
  const int ob = wid * 32;  // 32 output channels per wave (2 n-tiles)

  const float bv0 = bias[ob + l];
  const float bv1 = bias[ob + 16 + l];

  f32x4 acc0 = {0.f, 0.f, 0.f, 0.f};
  f32x4 acc1 = {0.f, 0.f, 0.f, 0.f};

  const unsigned short* wp0 = Wb + (size_t)(ob + l) * KPAD + q * 8;
  const unsigned short* wp1 = wp0 + (size_t)16 * KPAD;
  const float* wf0 = W + (size_t)(ob + l) * KREAL + q * 8;
  const float* wf1 = wf0 + (size_t)16 * KREAL;

#pragma unroll 2
  for (int kt = 0; kt < NKT; ++kt) {
    const bf16x8 a = *reinterpret_cast<const bf16x8*>(
        s_p + l * PSTR + kt * 32 + q * 8);
    ABFrag b0, b1;
    if (useWb) {
      b0.u = *reinterpret_cast<const uint4*>(wp0 + kt * 32);
      b1.u = *reinterpret_cast<const uint4*>(wp1 + kt * 32);
    } else {
      const int kb = kt * 32 + q * 8;
      b0.u = make_uint4(0, 0, 0, 0);
      b1.u = make_uint4(0, 0, 0, 0);
      if (kb < KREAL) {
        const float4* s0 = reinterpret_cast<const float4*>(wf0 + kt * 32);
        const float4* s1 = reinterpret_cast<const float4*>(wf1 + kt * 32);
        const float4 x0 = s0[0], x1 = s0[1];
        const float4 y0 = s1[0], y1 = s1[1];
        b0.u = make_uint4(pack_bf2(x0.x, x0.y), pack_bf2(x0.z, x0.w),
                          pack_bf2(x1.x, x1.y), pack_bf2(x1.z, x1.w));
        b1.u = make_uint4(pack_bf2(y0.x, y0.y), pack_bf2(y0.z, y0.w),
                          pack_bf2(y1.x, y1.y), pack_bf2(y1.z, y1.w));
      }
    }
    acc0 = __builtin_amdgcn_mfma_f32_16x16x32_bf16(a, b0.v, acc0, 0, 0, 0);
    acc1 = __builtin_amdgcn_mfma_f32_16x16x32_bf16(a, b1.v, acc1, 0, 0, 0);
  }

  // epilogue: C/D layout col=lane&15 (=n), row=quad*4+reg (=m)
  const int mrow = blockIdx.x * MT + q * 4;
#pragma unroll
  for (int r = 0; r < 4; ++r) {
    out[(size_t)(mrow + r) * COUT + ob + l]      = acc0[r] + bv0;
    out[(size_t)(mrow + r) * COUT + ob + 16 + l] = acc1[r] + bv1;
  }
}

extern "C" void kernel_launch(void* const* d_in, const int* in_sizes, int n_in,
                              void* d_out, int out_size, void* d_ws, size_t ws_size,
                              hipStream_t stream) {
  const float* feat = (const float*)d_in[0];
  const int*   nidx = (const int*)d_in[1];
  const float* wn   = (const float*)d_in[2];
  const float* addf = (const float*)d_in[3];
  const float* W    = (const float*)d_in[4];
  const float* bias = (const float*)d_in[5];
  float* out = (float*)d_out;

  unsigned short* Wb = (unsigned short*)d_ws;
  const int useWb = (ws_size >= (size_t)COUT * KPAD * 2) ? 1 : 0;
  if (useWb) {
    convert_w<<<COUT, 256, 0, stream>>>(W, Wb);
  }
  const int nblocks = (2 * NPTS) / MT;  // 8192
  pconv_fused<<<nblocks, 256, 0, stream>>>(feat, nidx, wn, addf, W, bias, Wb, useWb, out);
}

// Round 4
// 553.040 us; speedup vs baseline: 1.0260x; 1.0260x over previous
//
#include <hip/hip_runtime.h>
#include <hip/hip_bf16.h>

namespace {
constexpr int NPTS  = 65536;
constexpr int KNB   = 16;
constexpr int CMID  = 16;
constexpr int CIN   = 64;
constexpr int CADD  = 3;
constexpr int COUT  = 128;
constexpr int KREAL = 1072;      // 67*16
constexpr int KPAD  = 1088;      // 68*16
constexpr int MT    = 16;        // points per block
constexpr int PSTR  = 1096;      // s_p row stride (shorts); 2192 B = 16-B aligned
constexpr int NKT   = KPAD / 32; // 34

// per-wave transpose scratch (shorts), rows have 32 k-slots (upper 16 stay zero)
constexpr int WNT_OFF  = 0;      // wn^T: 16 rows(j) x 32
constexpr int FEAT_OFF = 512;    // feat^T: 80 rows(c) x 32 (rows 67..79 stay zero)
constexpr int SCR      = 512 + 80 * 32;  // 3072 shorts = 6144 B per wave
}

typedef __attribute__((ext_vector_type(8))) __bf16 bf16x8;
typedef __attribute__((ext_vector_type(4))) float f32x4;

union ABFrag { bf16x8 v; uint4 u; };

__device__ __forceinline__ unsigned short bf(float x) {
  __hip_bfloat16 h = __float2bfloat16(x);
  return *reinterpret_cast<unsigned short*>(&h);
}
__device__ __forceinline__ unsigned int pack_bf2(float a, float b) {
  __hip_bfloat162 h = __float22bfloat162_rn(make_float2(a, b));
  return *reinterpret_cast<unsigned int*>(&h);
}

// One-time per launch: W [128][1072] f32 -> bf16 zero-padded [128][1088] in workspace.
__global__ void convert_w(const float* __restrict__ W, unsigned short* __restrict__ Wb) {
  const int o = blockIdx.x;
  for (int k = threadIdx.x; k < KPAD; k += blockDim.x) {
    float v = (k < KREAL) ? W[o * KREAL + k] : 0.0f;
    Wb[o * KPAD + k] = bf(v);
  }
}

__global__ __launch_bounds__(256, 2) void pconv_fused(
    const float* __restrict__ feat,        // [2][65536][64]
    const int* __restrict__ nidx,          // [2][65536][16]
    const float* __restrict__ wn,          // [2][65536][16][16]
    const float* __restrict__ addf,        // [2][65536][16][3]
    const float* __restrict__ W,           // [128][1072] f32 (fallback)
    const float* __restrict__ bias,        // [128]
    const unsigned short* __restrict__ Wb, // [128][1088] bf16
    int useWb,
    float* __restrict__ out)               // [2][65536][128]
{
  __shared__ __align__(16) unsigned short s_p[MT * PSTR];  // 35072 B
  __shared__ __align__(16) unsigned short s_x[4 * SCR];    // 24576 B

  const int tid  = threadIdx.x;
  const int wid  = tid >> 6;
  const int lane = tid & 63;
  const int q    = lane >> 4;
  const int l    = lane & 15;
  const int kq   = lane >> 2;   // stage-1 load: neighbor slot (0..15)
  const int sub  = lane & 3;    // stage-1 load: sub-slot

  unsigned short* scr = s_x + wid * SCR;

  // ---------------- stage 1: per-point MFMA pconv^T -> s_p ----------------
  {
    // Zero entire scratch once: provides k=16..31 zero-padding and c=67..79 pad rows.
    // 6144 B = 64 lanes x 6 x 16 B.
#pragma unroll
    for (int t = 0; t < 6; ++t)
      *reinterpret_cast<uint4*>(scr + (t * 64 + lane) * 8) = make_uint4(0, 0, 0, 0);

    const f32x4 zacc = {0.f, 0.f, 0.f, 0.f};

    for (int pl = 0; pl < 4; ++pl) {
      const int p  = wid * 4 + pl;
      const int mg = blockIdx.x * MT + p;
      const int b  = mg >> 16;
      const float* fb = feat + (size_t)b * (NPTS * CIN);

      // 7 VMEM instrs total for this point:
      const int nb = nidx[(size_t)mg * KNB + kq];                              // 1
      const float4 wv = *reinterpret_cast<const float4*>(
          wn + (size_t)mg * (KNB * CMID) + kq * CMID + sub * 4);               // 1
      const float* fr = fb + (size_t)nb * CIN + sub * 4;
      const float4 fv0 = *reinterpret_cast<const float4*>(fr);                 // 4
      const float4 fv1 = *reinterpret_cast<const float4*>(fr + 16);
      const float4 fv2 = *reinterpret_cast<const float4*>(fr + 32);
      const float4 fv3 = *reinterpret_cast<const float4*>(fr + 48);
      float av = 0.f;
      if (sub < CADD)
        av = addf[(size_t)mg * (KNB * CADD) + kq * CADD + sub];                // 1

      // Transpose into per-wave scratch (LDS pipe).
      // wn^T[j][k] = wn[k][j]
      scr[WNT_OFF + (sub * 4 + 0) * 32 + kq] = bf(wv.x);
      scr[WNT_OFF + (sub * 4 + 1) * 32 + kq] = bf(wv.y);
      scr[WNT_OFF + (sub * 4 + 2) * 32 + kq] = bf(wv.z);
      scr[WNT_OFF + (sub * 4 + 3) * 32 + kq] = bf(wv.w);
      // feat^T[c][k] = feat[nb(k)][c]
      {
        unsigned short* fz = scr + FEAT_OFF + (sub * 4) * 32 + kq;
        fz[0 * 32] = bf(fv0.x); fz[1 * 32] = bf(fv0.y); fz[2 * 32] = bf(fv0.z); fz[3 * 32] = bf(fv0.w);
        unsigned short* f1 = fz + 16 * 32;
        f1[0 * 32] = bf(fv1.x); f1[1 * 32] = bf(fv1.y); f1[2 * 32] = bf(fv1.z); f1[3 * 32] = bf(fv1.w);
        unsigned short* f2 = fz + 32 * 32;
        f2[0 * 32] = bf(fv2.x); f2[1 * 32] = bf(fv2.y); f2[2 * 32] = bf(fv2.z); f2[3 * 32] = bf(fv2.w);
        unsigned short* f3 = fz + 48 * 32;
        f3[0 * 32] = bf(fv3.x); f3[1 * 32] = bf(fv3.y); f3[2 * 32] = bf(fv3.z); f3[3 * 32] = bf(fv3.w);
      }
      if (sub < CADD)
        scr[FEAT_OFF + (64 + sub) * 32 + kq] = bf(av);

      // Fragments: A[m=j][k=nb] from wn^T, B[k=nb][n=c] from feat^T.
      const bf16x8 a = *reinterpret_cast<const bf16x8*>(scr + WNT_OFF + l * 32 + q * 8);
      unsigned short* prow = s_p + p * PSTR;

#pragma unroll
      for (int ct = 0; ct < 5; ++ct) {
        const bf16x8 bfr = *reinterpret_cast<const bf16x8*>(
            scr + FEAT_OFF + (ct * 16 + l) * 32 + q * 8);
        const f32x4 d = __builtin_amdgcn_mfma_f32_16x16x32_bf16(a, bfr, zacc, 0, 0, 0);
        // D[row=j=q*4+r][col=c=ct*16+l] -> s_p[p][c*16+j]
        if (ct < 4 || l < 4) {
          uint2 w2;
          w2.x = pack_bf2(d[0], d[1]);
          w2.y = pack_bf2(d[2], d[3]);
          *reinterpret_cast<uint2*>(prow + (ct * 16 + l) * 16 + q * 4) = w2;
        }
      }
    }
  }

  __syncthreads();  // the ONLY barrier

  // ---------------- stage 2: out[16][128] = pconv[16][1088] @ Wb^T ----------------
  const int ob = wid * 32;

  const float bv0 = bias[ob + l];
  const float bv1 = bias[ob + 16 + l];

  f32x4 acc0 = {0.f, 0.f, 0.f, 0.f};
  f32x4 acc1 = {0.f, 0.f, 0.f, 0.f};

  const unsigned short* wp0 = Wb + (size_t)(ob + l) * KPAD + q * 8;
  const unsigned short* wp1 = wp0 + (size_t)16 * KPAD;
  const float* wf0 = W + (size_t)(ob + l) * KREAL + q * 8;
  const float* wf1 = wf0 + (size_t)16 * KREAL;

#pragma unroll 2
  for (int kt = 0; kt < NKT; ++kt) {
    const bf16x8 a = *reinterpret_cast<const bf16x8*>(
        s_p + l * PSTR + kt * 32 + q * 8);
    ABFrag b0, b1;
    if (useWb) {
      b0.u = *reinterpret_cast<const uint4*>(wp0 + kt * 32);
      b1.u = *reinterpret_cast<const uint4*>(wp1 + kt * 32);
    } else {
      const int kb = kt * 32 + q * 8;
      b0.u = make_uint4(0, 0, 0, 0);
      b1.u = make_uint4(0, 0, 0, 0);
      if (kb < KREAL) {
        const float4* s0 = reinterpret_cast<const float4*>(wf0 + kt * 32);
        const float4* s1 = reinterpret_cast<const float4*>(wf1 + kt * 32);
        const float4 x0 = s0[0], x1 = s0[1];
        const float4 y0 = s1[0], y1 = s1[1];
        b0.u = make_uint4(pack_bf2(x0.x, x0.y), pack_bf2(x0.z, x0.w),
                          pack_bf2(x1.x, x1.y), pack_bf2(x1.z, x1.w));
        b1.u = make_uint4(pack_bf2(y0.x, y0.y), pack_bf2(y0.z, y0.w),
                          pack_bf2(y1.x, y1.y), pack_bf2(y1.z, y1.w));
      }
    }
    acc0 = __builtin_amdgcn_mfma_f32_16x16x32_bf16(a, b0.v, acc0, 0, 0, 0);
    acc1 = __builtin_amdgcn_mfma_f32_16x16x32_bf16(a, b1.v, acc1, 0, 0, 0);
  }

  const int mrow = blockIdx.x * MT + q * 4;
#pragma unroll
  for (int r = 0; r < 4; ++r) {
    out[(size_t)(mrow + r) * COUT + ob + l]      = acc0[r] + bv0;
    out[(size_t)(mrow + r) * COUT + ob + 16 + l] = acc1[r] + bv1;
  }
}

extern "C" void kernel_launch(void* const* d_in, const int* in_sizes, int n_in,
                              void* d_out, int out_size, void* d_ws, size_t ws_size,
                              hipStream_t stream) {
  const float* feat = (const float*)d_in[0];
  const int*   nidx = (const int*)d_in[1];
  const float* wn   = (const float*)d_in[2];
  const float* addf = (const float*)d_in[3];
  const float* W    = (const float*)d_in[4];
  const float* bias = (const float*)d_in[5];
  float* out = (float*)d_out;

  unsigned short* Wb = (unsigned short*)d_ws;
  const int useWb = (ws_size >= (size_t)COUT * KPAD * 2) ? 1 : 0;
  if (useWb) {
    convert_w<<<COUT, 256, 0, stream>>>(W, Wb);
  }
  const int nblocks = (2 * NPTS) / MT;  // 8192
  pconv_fused<<<nblocks, 256, 0, stream>>>(feat, nidx, wn, addf, W, bias, Wb, useWb, out);
}

// Round 5
// 513.254 us; speedup vs baseline: 1.1055x; 1.0775x over previous
//
#include <hip/hip_runtime.h>
#include <hip/hip_bf16.h>

namespace {
constexpr int NPTS  = 65536;
constexpr int KNB   = 16;
constexpr int CMID  = 16;
constexpr int CIN   = 64;
constexpr int CADD  = 3;
constexpr int COUT  = 128;
constexpr int KREAL = 1072;      // 67*16
constexpr int KPAD  = 1088;      // 68*16
constexpr int MT    = 16;        // points per block
constexpr int PSTR  = 1096;      // s_p row stride (shorts)
constexpr int NKT   = KPAD / 32; // 34

constexpr int WNT_OFF  = 0;               // wn^T: 16 rows(j) x 32
constexpr int FEAT_OFF = 512;             // feat^T: 80 rows(c) x 32
constexpr int SCR      = 512 + 80 * 32;   // 3072 shorts = 6144 B per wave
}

typedef __attribute__((ext_vector_type(8))) __bf16 bf16x8;
typedef __attribute__((ext_vector_type(4))) float f32x4;
typedef __attribute__((ext_vector_type(4))) float f32x4v;  // for nontemporal vec loads

union ABFrag { bf16x8 v; uint4 u; };

__device__ __forceinline__ unsigned short bf(float x) {
  __hip_bfloat16 h = __float2bfloat16(x);
  return *reinterpret_cast<unsigned short*>(&h);
}
__device__ __forceinline__ unsigned int pack_bf2(float a, float b) {
  __hip_bfloat162 h = __float22bfloat162_rn(make_float2(a, b));
  return *reinterpret_cast<unsigned int*>(&h);
}

// One-time per launch: W [128][1072] f32 -> bf16 zero-padded [128][1088].
__global__ void convert_w(const float* __restrict__ W, unsigned short* __restrict__ Wb) {
  const int o = blockIdx.x;
  for (int k = threadIdx.x; k < KPAD; k += blockDim.x) {
    float v = (k < KREAL) ? W[o * KREAL + k] : 0.0f;
    Wb[o * KPAD + k] = bf(v);
  }
}

__global__ __launch_bounds__(256, 2) void pconv_fused(
    const float* __restrict__ feat,        // [2][65536][64]  (cacheable: LLC-resident)
    const int* __restrict__ nidx,          // [2][65536][16]  (nt: streamed once)
    const float* __restrict__ wn,          // [2][65536][16][16] (nt: streamed once)
    const float* __restrict__ addf,        // [2][65536][16][3]  (nt: streamed once)
    const float* __restrict__ W,           // [128][1072] f32 (fallback)
    const float* __restrict__ bias,        // [128]
    const unsigned short* __restrict__ Wb, // [128][1088] bf16 (cacheable: reused)
    int useWb,
    float* __restrict__ out)               // [2][65536][128] (nt stores)
{
  __shared__ __align__(16) unsigned short s_p[MT * PSTR];  // 35072 B
  __shared__ __align__(16) unsigned short s_x[4 * SCR];    // 24576 B

  const int tid  = threadIdx.x;
  const int wid  = tid >> 6;
  const int lane = tid & 63;
  const int q    = lane >> 4;
  const int l    = lane & 15;
  const int kq   = lane >> 2;   // stage-1: neighbor slot (0..15)
  const int sub  = lane & 3;    // stage-1: sub-slot

  unsigned short* scr = s_x + wid * SCR;

  // ---------------- stage 1: per-point MFMA pconv^T -> s_p ----------------
  {
    // Zero scratch once (k=16..31 padding + c=67..79 pad rows).
#pragma unroll
    for (int t = 0; t < 6; ++t)
      *reinterpret_cast<uint4*>(scr + (t * 64 + lane) * 8) = make_uint4(0, 0, 0, 0);

    const int mg0 = blockIdx.x * MT + wid * 4;
    const int b   = (blockIdx.x * MT) >> 16;   // whole block in one batch
    const float* fb = feat + (size_t)b * (NPTS * CIN);

    // ---- phase 1: batched loads for all 4 points (max MLP) ----
    int nb[4];
#pragma unroll
    for (int pl = 0; pl < 4; ++pl)
      nb[pl] = __builtin_nontemporal_load(nidx + (size_t)(mg0 + pl) * KNB + kq);

    f32x4v wv[4];
    float  av[4];
#pragma unroll
    for (int pl = 0; pl < 4; ++pl) {
      const int mg = mg0 + pl;
      wv[pl] = __builtin_nontemporal_load(reinterpret_cast<const f32x4v*>(
          wn + (size_t)mg * (KNB * CMID) + kq * CMID + sub * 4));
      av[pl] = 0.f;
      if (sub < CADD)
        av[pl] = __builtin_nontemporal_load(
            addf + (size_t)mg * (KNB * CADD) + kq * CADD + sub);
    }

    f32x4v fv[4][4];  // feat stays cacheable — it is the reused array
#pragma unroll
    for (int pl = 0; pl < 4; ++pl) {
      const float* fr = fb + (size_t)nb[pl] * CIN + sub * 4;
#pragma unroll
      for (int t = 0; t < 4; ++t)
        fv[pl][t] = *reinterpret_cast<const f32x4v*>(fr + 16 * t);
    }

    // ---- phase 2: per point transpose -> frags -> MFMA -> s_p ----
    const f32x4 zacc = {0.f, 0.f, 0.f, 0.f};
#pragma unroll
    for (int pl = 0; pl < 4; ++pl) {
      const int p = wid * 4 + pl;

      // wn^T[j][k]
      scr[WNT_OFF + (sub * 4 + 0) * 32 + kq] = bf(wv[pl].x);
      scr[WNT_OFF + (sub * 4 + 1) * 32 + kq] = bf(wv[pl].y);
      scr[WNT_OFF + (sub * 4 + 2) * 32 + kq] = bf(wv[pl].z);
      scr[WNT_OFF + (sub * 4 + 3) * 32 + kq] = bf(wv[pl].w);
      // feat^T[c][k]
#pragma unroll
      for (int t = 0; t < 4; ++t) {
        unsigned short* fz = scr + FEAT_OFF + (t * 16 + sub * 4) * 32 + kq;
        fz[0 * 32] = bf(fv[pl][t].x);
        fz[1 * 32] = bf(fv[pl][t].y);
        fz[2 * 32] = bf(fv[pl][t].z);
        fz[3 * 32] = bf(fv[pl][t].w);
      }
      if (sub < CADD)
        scr[FEAT_OFF + (64 + sub) * 32 + kq] = bf(av[pl]);

      const bf16x8 a = *reinterpret_cast<const bf16x8*>(scr + WNT_OFF + l * 32 + q * 8);
      unsigned short* prow = s_p + p * PSTR;

#pragma unroll
      for (int ct = 0; ct < 5; ++ct) {
        const bf16x8 bfr = *reinterpret_cast<const bf16x8*>(
            scr + FEAT_OFF + (ct * 16 + l) * 32 + q * 8);
        const f32x4 d = __builtin_amdgcn_mfma_f32_16x16x32_bf16(a, bfr, zacc, 0, 0, 0);
        if (ct < 4 || l < 4) {
          uint2 w2;
          w2.x = pack_bf2(d[0], d[1]);
          w2.y = pack_bf2(d[2], d[3]);
          *reinterpret_cast<uint2*>(prow + (ct * 16 + l) * 16 + q * 4) = w2;
        }
      }
    }
  }

  __syncthreads();  // the ONLY barrier

  // ---------------- stage 2: out[16][128] = pconv[16][1088] @ Wb^T ----------------
  const int ob = wid * 32;

  const float bv0 = bias[ob + l];
  const float bv1 = bias[ob + 16 + l];

  f32x4 acc0 = {0.f, 0.f, 0.f, 0.f};
  f32x4 acc1 = {0.f, 0.f, 0.f, 0.f};

  const unsigned short* wp0 = Wb + (size_t)(ob + l) * KPAD + q * 8;
  const unsigned short* wp1 = wp0 + (size_t)16 * KPAD;
  const float* wf0 = W + (size_t)(ob + l) * KREAL + q * 8;
  const float* wf1 = wf0 + (size_t)16 * KREAL;

#pragma unroll 2
  for (int kt = 0; kt < NKT; ++kt) {
    const bf16x8 a = *reinterpret_cast<const bf16x8*>(
        s_p + l * PSTR + kt * 32 + q * 8);
    ABFrag b0, b1;
    if (useWb) {
      b0.u = *reinterpret_cast<const uint4*>(wp0 + kt * 32);
      b1.u = *reinterpret_cast<const uint4*>(wp1 + kt * 32);
    } else {
      const int kb = kt * 32 + q * 8;
      b0.u = make_uint4(0, 0, 0, 0);
      b1.u = make_uint4(0, 0, 0, 0);
      if (kb < KREAL) {
        const float4* s0 = reinterpret_cast<const float4*>(wf0 + kt * 32);
        const float4* s1 = reinterpret_cast<const float4*>(wf1 + kt * 32);
        const float4 x0 = s0[0], x1 = s0[1];
        const float4 y0 = s1[0], y1 = s1[1];
        b0.u = make_uint4(pack_bf2(x0.x, x0.y), pack_bf2(x0.z, x0.w),
                          pack_bf2(x1.x, x1.y), pack_bf2(x1.z, x1.w));
        b1.u = make_uint4(pack_bf2(y0.x, y0.y), pack_bf2(y0.z, y0.w),
                          pack_bf2(y1.x, y1.y), pack_bf2(y1.z, y1.w));
      }
    }
    acc0 = __builtin_amdgcn_mfma_f32_16x16x32_bf16(a, b0.v, acc0, 0, 0, 0);
    acc1 = __builtin_amdgcn_mfma_f32_16x16x32_bf16(a, b1.v, acc1, 0, 0, 0);
  }

  // epilogue: nt stores (out is never re-read)
  const int mrow = blockIdx.x * MT + q * 4;
#pragma unroll
  for (int r = 0; r < 4; ++r) {
    __builtin_nontemporal_store(acc0[r] + bv0, out + (size_t)(mrow + r) * COUT + ob + l);
    __builtin_nontemporal_store(acc1[r] + bv1, out + (size_t)(mrow + r) * COUT + ob + 16 + l);
  }
}

extern "C" void kernel_launch(void* const* d_in, const int* in_sizes, int n_in,
                              void* d_out, int out_size, void* d_ws, size_t ws_size,
                              hipStream_t stream) {
  const float* feat = (const float*)d_in[0];
  const int*   nidx = (const int*)d_in[1];
  const float* wn   = (const float*)d_in[2];
  const float* addf = (const float*)d_in[3];
  const float* W    = (const float*)d_in[4];
  const float* bias = (const float*)d_in[5];
  float* out = (float*)d_out;

  unsigned short* Wb = (unsigned short*)d_ws;
  const int useWb = (ws_size >= (size_t)COUT * KPAD * 2) ? 1 : 0;
  if (useWb) {
    convert_w<<<COUT, 256, 0, stream>>>(W, Wb);
  }
  const int nblocks = (2 * NPTS) / MT;  // 8192
  pconv_fused<<<nblocks, 256, 0, stream>>>(feat, nidx, wn, addf, W, bias, Wb, useWb, out);
}